// Round 1
// baseline (651.104 us; speedup 1.0000x reference)
//
#include <hip/hip_runtime.h>
#include <cstddef>
#include <cstdint>

// Problem dims
// B=4096, IN=1024, F=512, HID=128, D=128, RH=64, OUT=1, C=10, R=16
//
// Collapse: out[r,b] = x[b,:]·Wfin[r,:] + bfin[r]
//   Weff[r,f] = sum_{c,h,d} w[r,c] W2[r,h] rv[r,d] fc1_w[c,h*512+f,d]
//             + sum_{c,h}   w[r,c] W2[r,h] fc1_b[c,h*512+f]
//   Wfin[r,i] = sum_f Weff[r,f] base_w[f,i]
//   bfin[r]   = sum_f Weff[r,f] base_b[f] + sum_h W2[r,h] b1[r,h] + b2[r]
//   (b1,b2 expanded through the same hyper() linearity)

// ws float offsets
#define WS_WT    0        // 160    wT[c*16+r]
#define WS_RV    160      // 2048   rv[r*128+d]
#define WS_W2T   2208     // 2048   W2T[h*16+r]
#define WS_WEFF  4256     // 8192   Weff[r*512+f]
#define WS_WFIN  12448    // 16384  Wfin[r*1024+i]
#define WS_BFIN  28832    // 16
#define WS_R1    28848    // 1024   r1[r*64+o]
#define WS_ZERO_BEG WS_WEFF
#define WS_ZERO_CNT (WS_BFIN + 16 - WS_WEFF)   // 24592 floats

__device__ __forceinline__ void load_coef(const float* __restrict__ WT,
                                          const float* __restrict__ W2T,
                                          int c, int h, float* cw) {
  // coef[r] = w[r,c] * W2[r,h]; both arrays transposed so 16 r are contiguous
  const float4* wc4 = (const float4*)(WT + c * 16);
  const float4* w24 = (const float4*)(W2T + h * 16);
  float4 a0 = wc4[0], a1 = wc4[1], a2 = wc4[2], a3 = wc4[3];
  float4 c0 = w24[0], c1 = w24[1], c2 = w24[2], c3 = w24[3];
  cw[0]  = a0.x * c0.x; cw[1]  = a0.y * c0.y; cw[2]  = a0.z * c0.z; cw[3]  = a0.w * c0.w;
  cw[4]  = a1.x * c1.x; cw[5]  = a1.y * c1.y; cw[6]  = a1.z * c1.z; cw[7]  = a1.w * c1.w;
  cw[8]  = a2.x * c2.x; cw[9]  = a2.y * c2.y; cw[10] = a2.z * c2.z; cw[11] = a2.w * c2.w;
  cw[12] = a3.x * c3.x; cw[13] = a3.y * c3.y; cw[14] = a3.z * c3.z; cw[15] = a3.w * c3.w;
}

// ---------------- K1: tiny MLP front chain (1 block) ----------------
__global__ __launch_bounds__(256) void k_front(
    const float* __restrict__ pref, const float* __restrict__ wm1_w,
    const float* __restrict__ wm1_b, const float* __restrict__ wm2_w,
    const float* __restrict__ wm2_b, const float* __restrict__ ray0_w,
    const float* __restrict__ ray0_b, const float* __restrict__ ray2_b,
    const float* __restrict__ fc2_b, float* __restrict__ ws) {
  __shared__ float sh1[16][16];
  __shared__ float sw[16][10];
  __shared__ float sinv[16];
  const int t = threadIdx.x;
  {
    int r = t >> 4, j = t & 15;
    float v = pref[r * 2 + 0] * wm1_w[j * 2 + 0] + pref[r * 2 + 1] * wm1_w[j * 2 + 1] + wm1_b[j];
    sh1[r][j] = fmaxf(v, 0.f);
  }
  __syncthreads();
  if (t < 160) {
    int r = t / 10, c = t % 10;
    float z = wm2_b[c];
    for (int j = 0; j < 16; ++j) z += sh1[r][j] * wm2_w[c * 16 + j];
    sw[r][c] = 1.f / (1.f + expf(-z));
  }
  __syncthreads();
  if (t < 16) {
    float s = 0.f;
    for (int c = 0; c < 10; ++c) s += sw[t][c];
    sinv[t] = 1.f / s;
  }
  __syncthreads();
  if (t < 160) {
    int r = t / 10, c = t % 10;
    float v = sw[r][c] * sinv[r];
    sw[r][c] = v;
    ws[WS_WT + c * 16 + r] = v;
  }
  __syncthreads();
  // r1[r,o] = relu(pref[r,:]·m0w[r,o,:] + (w@ray0_b)[r,o])
  for (int it = t; it < 1024; it += 256) {
    int r = it >> 6, o = it & 63;
    float m0 = 0.f, m1 = 0.f, rb = 0.f;
    for (int c = 0; c < 10; ++c) {
      float wv = sw[r][c];
      m0 += wv * ray0_w[(c * 64 + o) * 2 + 0];
      m1 += wv * ray0_w[(c * 64 + o) * 2 + 1];
      rb += wv * ray0_b[c * 64 + o];
    }
    float v = pref[r * 2 + 0] * m0 + pref[r * 2 + 1] * m1 + rb;
    ws[WS_R1 + it] = fmaxf(v, 0.f);
  }
  // rv init = (w @ ray2_b)[r,d]   (ray2_w part added by k_rv)
  for (int it = t; it < 2048; it += 256) {
    int r = it >> 7, d = it & 127;
    float a = 0.f;
    for (int c = 0; c < 10; ++c) a += sw[r][c] * ray2_b[c * 128 + d];
    ws[WS_RV + it] = a;
  }
  // W2T init = (w @ fc2_b) transposed: W2T[h*16+r]
  for (int it = t; it < 2048; it += 256) {
    int h = it >> 4, r = it & 15;
    float a = 0.f;
    for (int c = 0; c < 10; ++c) a += sw[r][c] * fc2_b[c * 128 + h];
    ws[WS_W2T + it] = a;
  }
}

// ---------------- K2: rv += w[r,c] * (ray2_w[c,d,:]·r1[r,:]) ----------------
__global__ __launch_bounds__(256) void k_rv(const float* __restrict__ ray2_w,
                                            float* __restrict__ ws) {
  __shared__ float r1s[16 * 65];
  const int t = threadIdx.x;
  for (int k = t; k < 1024; k += 256) r1s[(k >> 6) * 65 + (k & 63)] = ws[WS_R1 + k];
  __syncthreads();
  const int tid = blockIdx.x * 256 + t;   // 20480 = 1280 pairs x 16 r
  const int r = tid & 15;
  const int pair = tid >> 4;              // c*128+d
  const float4* row4 = (const float4*)(ray2_w + (size_t)pair * 64);
  const float* r1r = r1s + r * 65;
  float dot = 0.f;
#pragma unroll
  for (int k = 0; k < 16; ++k) {
    float4 a = row4[k];
    dot += a.x * r1r[k * 4 + 0] + a.y * r1r[k * 4 + 1] + a.z * r1r[k * 4 + 2] + a.w * r1r[k * 4 + 3];
  }
  int c = pair >> 7, d = pair & 127;
  atomicAdd(&ws[WS_RV + r * 128 + d], ws[WS_WT + c * 16 + r] * dot);
}

// ---------------- K3: W2T += w[r,c] * (fc2_w[c,h,:]·rv[r,:]) ----------------
__global__ __launch_bounds__(256) void k_w2(const float* __restrict__ fc2_w,
                                            float* __restrict__ ws) {
  const int t = threadIdx.x;
  const int lane = t & 63;
  const int wave = __builtin_amdgcn_readfirstlane(blockIdx.x * 4 + (t >> 6)); // 0..319
  float2 rv2[16];
#pragma unroll
  for (int r = 0; r < 16; ++r) rv2[r] = *(const float2*)&ws[WS_RV + r * 128 + lane * 2];
  for (int q = 0; q < 4; ++q) {
    int rid = wave * 4 + q;               // 0..1279
    int c = rid >> 7, h = rid & 127;
    float2 a = *(const float2*)&fc2_w[(size_t)rid * 128 + lane * 2];
    float u[16];
#pragma unroll
    for (int r = 0; r < 16; ++r) {
      float tt = a.x * rv2[r].x + a.y * rv2[r].y;
      u[r] = tt * ws[WS_WT + c * 16 + r];
    }
#pragma unroll
    for (int m = 1; m <= 4; m <<= 1) {
#pragma unroll
      for (int r = 0; r < 16; ++r) u[r] += __shfl_xor(u[r], m, 64);
    }
    if ((lane & 7) == 0) {
#pragma unroll
      for (int r = 0; r < 16; ++r) atomicAdd(&ws[WS_W2T + h * 16 + r], u[r]);
    }
  }
}

// ---------------- K4: the big stream (fc1_w 335MB) + fc1_b + b1_w roles ----------------
__global__ __launch_bounds__(256, 3) void k_main(
    const float* __restrict__ fc1_w, const float* __restrict__ fc1_b,
    const float* __restrict__ b1_w, const float* __restrict__ b1_b,
    const float* __restrict__ b2_w, const float* __restrict__ b2_b,
    float* __restrict__ ws) {
  const int blk = blockIdx.x;
  const int t = threadIdx.x;
  const float* WT = ws + WS_WT;
  const float* W2T = ws + WS_W2T;
  const float* RV = ws + WS_RV;

  if (blk < 1024) {
    // Role S: stream fc1_w. wave owns f-pair, iterates 80 (c,h) rows.
    const int lane = t & 63;
    const int wave = __builtin_amdgcn_readfirstlane(blk * 4 + (t >> 6)); // 0..4095
    const int fp = wave & 255;          // f-pair
    const int ch0 = (wave >> 8) * 80;   // 16 chunks x 80 rows
    const int l32 = lane & 31;
    float4 rvq[16];
#pragma unroll
    for (int r = 0; r < 16; ++r) rvq[r] = *(const float4*)&RV[r * 128 + l32 * 4];
    float acc[16];
#pragma unroll
    for (int r = 0; r < 16; ++r) acc[r] = 0.f;

    const float4* p = (const float4*)fc1_w + (size_t)ch0 * 16384 + fp * 64 + lane;

    auto sstep = [&](const float4& av, int ch) {
      int c = ch >> 7, h = ch & 127;
      float cw[16];
      load_coef(WT, W2T, c, h, cw);
#pragma unroll
      for (int r = 0; r < 16; ++r) {
        float tt = av.x * rvq[r].x + av.y * rvq[r].y + av.z * rvq[r].z + av.w * rvq[r].w;
        acc[r] = fmaf(cw[r], tt, acc[r]);
      }
    };

    float4 a = *p; p += 16384;
    for (int it = 0; it < 79; ++it) {
      float4 an = *p; p += 16384;
      sstep(a, ch0 + it);
      a = an;
    }
    sstep(a, ch0 + 79);

#pragma unroll
    for (int m = 1; m <= 16; m <<= 1) {
#pragma unroll
      for (int r = 0; r < 16; ++r) acc[r] += __shfl_xor(acc[r], m, 64);
    }
    if (l32 == 0) {
      const int f = fp * 2 + (lane >> 5);
#pragma unroll
      for (int r = 0; r < 16; ++r) atomicAdd(&ws[WS_WEFF + r * 512 + f], acc[r]);
    }
  } else if (blk < 1040) {
    // Role B1: Weff += coef * fc1_b
    const int bb = blk - 1024;          // 0..15
    const int f = (bb & 1) * 256 + t;
    const int ch0 = __builtin_amdgcn_readfirstlane((bb >> 1) * 160);
    float acc[16];
#pragma unroll
    for (int r = 0; r < 16; ++r) acc[r] = 0.f;
    for (int it = 0; it < 160; ++it) {
      const int ch = ch0 + it;
      const int c = ch >> 7, h = ch & 127;
      float xb = fc1_b[(size_t)c * 65536 + h * 512 + f];
      float cw[16];
      load_coef(WT, W2T, c, h, cw);
#pragma unroll
      for (int r = 0; r < 16; ++r) acc[r] = fmaf(cw[r], xb, acc[r]);
    }
#pragma unroll
    for (int r = 0; r < 16; ++r) atomicAdd(&ws[WS_WEFF + r * 512 + f], acc[r]);
  } else {
    // Role H: bfin (b1_w stream + small bias terms)
    const int lane = t & 63;
    const int wave = __builtin_amdgcn_readfirstlane((blk - 1040) * 4 + (t >> 6)); // 0..7
    float2 rv2[16];
#pragma unroll
    for (int r = 0; r < 16; ++r) rv2[r] = *(const float2*)&RV[r * 128 + lane * 2];
    float acc[16];
#pragma unroll
    for (int r = 0; r < 16; ++r) acc[r] = 0.f;
    const int ch0 = wave * 160;
    for (int it = 0; it < 160; ++it) {
      const int ch = ch0 + it;
      const int c = ch >> 7, h = ch & 127;
      float2 a = *(const float2*)&b1_w[(size_t)ch * 128 + lane * 2];
      float cw[16];
      load_coef(WT, W2T, c, h, cw);
#pragma unroll
      for (int r = 0; r < 16; ++r)
        acc[r] = fmaf(cw[r], a.x * rv2[r].x + a.y * rv2[r].y, acc[r]);
    }
#pragma unroll
    for (int m = 1; m <= 32; m <<= 1) {
#pragma unroll
      for (int r = 0; r < 16; ++r) acc[r] += __shfl_xor(acc[r], m, 64);
    }
    if (lane == 0) {
#pragma unroll
      for (int r = 0; r < 16; ++r) atomicAdd(&ws[WS_BFIN + r], acc[r]);
    }
    if (wave == 7) {
      // small terms: coef·b1_b, (w·rv)·b2_w, w·b2_b
      float a2[16];
#pragma unroll
      for (int r = 0; r < 16; ++r) a2[r] = 0.f;
      for (int i = lane; i < 1280; i += 64) {
        int c = i >> 7, h = i & 127;
        float v = b1_b[c * 128 + h];
#pragma unroll
        for (int r = 0; r < 16; ++r)
          a2[r] = fmaf(WT[c * 16 + r] * W2T[h * 16 + r], v, a2[r]);
      }
      for (int i = lane; i < 1280; i += 64) {
        int c = i >> 7, d = i & 127;
        float v = b2_w[c * 128 + d];
#pragma unroll
        for (int r = 0; r < 16; ++r)
          a2[r] = fmaf(WT[c * 16 + r] * RV[r * 128 + d], v, a2[r]);
      }
      if (lane < 10) {
        float v = b2_b[lane];
#pragma unroll
        for (int r = 0; r < 16; ++r) a2[r] = fmaf(WT[lane * 16 + r], v, a2[r]);
      }
#pragma unroll
      for (int m = 1; m <= 32; m <<= 1) {
#pragma unroll
        for (int r = 0; r < 16; ++r) a2[r] += __shfl_xor(a2[r], m, 64);
      }
      if (lane == 0) {
#pragma unroll
        for (int r = 0; r < 16; ++r) atomicAdd(&ws[WS_BFIN + r], a2[r]);
      }
    }
  }
}

// ---------------- K5: Wfin = Weff @ base_w ; bfin += Weff·base_b ----------------
__global__ __launch_bounds__(256) void k_wfin(const float* __restrict__ base_w,
                                              const float* __restrict__ base_b,
                                              float* __restrict__ ws) {
  const int t = threadIdx.x;
  const int blk = blockIdx.x;             // 64 = 4 i-tiles x 16 f-chunks
  const int i = (blk & 3) * 256 + t;
  const int f0 = __builtin_amdgcn_readfirstlane((blk >> 2) * 32);
  const float* WEFF = ws + WS_WEFF;
  float acc[16];
#pragma unroll
  for (int r = 0; r < 16; ++r) acc[r] = 0.f;
#pragma unroll 4
  for (int f = f0; f < f0 + 32; ++f) {
    float bw = base_w[(size_t)f * 1024 + i];
#pragma unroll
    for (int r = 0; r < 16; ++r) acc[r] = fmaf(WEFF[r * 512 + f], bw, acc[r]);
  }
#pragma unroll
  for (int r = 0; r < 16; ++r) atomicAdd(&ws[WS_WFIN + r * 1024 + i], acc[r]);

  if (blk == 0 && t < 64) {
    float a2[16];
#pragma unroll
    for (int r = 0; r < 16; ++r) a2[r] = 0.f;
    for (int f = t; f < 512; f += 64) {
      float v = base_b[f];
#pragma unroll
      for (int r = 0; r < 16; ++r) a2[r] = fmaf(WEFF[r * 512 + f], v, a2[r]);
    }
#pragma unroll
    for (int m = 1; m <= 32; m <<= 1) {
#pragma unroll
      for (int r = 0; r < 16; ++r) a2[r] += __shfl_xor(a2[r], m, 64);
    }
    if (t == 0) {
#pragma unroll
      for (int r = 0; r < 16; ++r) atomicAdd(&ws[WS_BFIN + r], a2[r]);
    }
  }
}

// ---------------- K6: out[r,b] = x[b,:]·Wfin[r,:] + bfin[r]; sigmoid + raw ----------------
__global__ __launch_bounds__(256) void k_out(const float* __restrict__ x,
                                             const float* __restrict__ ws,
                                             float* __restrict__ out) {
  __shared__ float4 wfs[4096];            // 64 KB: Wfin as [r*256 + i4]
  const int t = threadIdx.x;
  const float4* wf4 = (const float4*)(ws + WS_WFIN);
#pragma unroll
  for (int k = 0; k < 16; ++k) wfs[t + 256 * k] = wf4[t + 256 * k];
  __syncthreads();

  const int b0 = blockIdx.x * 16;
  const int bp = t >> 5;                  // 0..7 (b-pair)
  const int isub = t & 31;
  const int bA = b0 + bp * 2;
  const float* xa = x + (size_t)bA * 1024;
  const float* xb = xa + 1024;
  float acc0[16], acc1[16];
#pragma unroll
  for (int r = 0; r < 16; ++r) { acc0[r] = 0.f; acc1[r] = 0.f; }

  for (int chunk = 0; chunk < 4; ++chunk) {
#pragma unroll
    for (int j = 0; j < 2; ++j) {
      const int off = chunk * 256 + j * 128 + isub * 4;
      float4 xv0 = *(const float4*)&xa[off];
      float4 xv1 = *(const float4*)&xb[off];
      const float4* wrow = wfs + chunk * 64 + j * 32 + isub;
#pragma unroll
      for (int r = 0; r < 16; ++r) {
        float4 w = wrow[r * 256];
        acc0[r] += xv0.x * w.x + xv0.y * w.y + xv0.z * w.z + xv0.w * w.w;
        acc1[r] += xv1.x * w.x + xv1.y * w.y + xv1.z * w.z + xv1.w * w.w;
      }
    }
  }
#pragma unroll
  for (int m = 1; m <= 16; m <<= 1) {
#pragma unroll
    for (int r = 0; r < 16; ++r) {
      acc0[r] += __shfl_xor(acc0[r], m, 64);
      acc1[r] += __shfl_xor(acc1[r], m, 64);
    }
  }
  if (isub == 0) {
#pragma unroll
    for (int r = 0; r < 16; ++r) {
      float bf = ws[WS_BFIN + r];
      float v0 = acc0[r] + bf;
      float v1 = acc1[r] + bf;
      out[r * 4096 + bA] = 1.f / (1.f + expf(-v0));
      out[r * 4096 + bA + 1] = 1.f / (1.f + expf(-v1));
      out[65536 + r * 4096 + bA] = v0;
      out[65536 + r * 4096 + bA + 1] = v1;
    }
  }
}

extern "C" void kernel_launch(void* const* d_in, const int* in_sizes, int n_in,
                              void* d_out, int out_size, void* d_ws, size_t ws_size,
                              hipStream_t stream) {
  (void)in_sizes; (void)n_in; (void)out_size; (void)ws_size;
  const float* x      = (const float*)d_in[0];
  const float* pref   = (const float*)d_in[1];
  const float* base_w = (const float*)d_in[2];
  const float* base_b = (const float*)d_in[3];
  const float* wm1_w  = (const float*)d_in[4];
  const float* wm1_b  = (const float*)d_in[5];
  const float* wm2_w  = (const float*)d_in[6];
  const float* wm2_b  = (const float*)d_in[7];
  const float* ray0_w = (const float*)d_in[8];
  const float* ray0_b = (const float*)d_in[9];
  const float* ray2_w = (const float*)d_in[10];
  const float* ray2_b = (const float*)d_in[11];
  const float* fc1_w  = (const float*)d_in[12];
  const float* fc1_b  = (const float*)d_in[13];
  const float* b1_w   = (const float*)d_in[14];
  const float* b1_b   = (const float*)d_in[15];
  const float* fc2_w  = (const float*)d_in[16];
  const float* fc2_b  = (const float*)d_in[17];
  const float* b2_w   = (const float*)d_in[18];
  const float* b2_b   = (const float*)d_in[19];
  float* ws  = (float*)d_ws;
  float* out = (float*)d_out;

  hipMemsetAsync(ws + WS_ZERO_BEG, 0, (size_t)WS_ZERO_CNT * sizeof(float), stream);
  k_front<<<1, 256, 0, stream>>>(pref, wm1_w, wm1_b, wm2_w, wm2_b,
                                 ray0_w, ray0_b, ray2_b, fc2_b, ws);
  k_rv<<<80, 256, 0, stream>>>(ray2_w, ws);
  k_w2<<<80, 256, 0, stream>>>(fc2_w, ws);
  k_main<<<1042, 256, 0, stream>>>(fc1_w, fc1_b, b1_w, b1_b, b2_w, b2_b, ws);
  k_wfin<<<64, 256, 0, stream>>>(base_w, base_b, ws);
  k_out<<<256, 256, 0, stream>>>(x, ws, out);
}

// Round 2
// 566.381 us; speedup vs baseline: 1.1496x; 1.1496x over previous
//
#include <hip/hip_runtime.h>
#include <cstddef>
#include <cstdint>

// B=4096, IN=1024, F=512, HID=128, D=128, RH=64, OUT=1, C=10, R=16
//
// out[r,b] = x[b,:]·Wfin[r,:] + bfin[r]
//   Weff[r,f] = sum_{c,h,d} w[r,c] W2[r,h] rv[r,d] fc1_w[c,h*512+f,d]
//             + sum_{c,h}   w[r,c] W2[r,h] fc1_b[c,h*512+f]
//   Wfin[r,i] = sum_f Weff[r,f] base_w[f,i]
//   bfin[r]   = sum_f Weff[r,f] base_b[f] + b1/b2 terms via hyper linearity

// ws float offsets
#define WS_WT    0        // 160    wT[c*16+r]
#define WS_RV    160      // 2048   rv[r*128+d]
#define WS_W2T   2208     // 2048   W2T[h*16+r]
#define WS_WEFF  4256     // 8192   Weff[r*512+f]
#define WS_WFIN  12448    // 16384  Wfin[r*1024+i]
#define WS_BFIN  28832    // 16
#define WS_ZERO_BEG WS_RV
#define WS_ZERO_CNT (WS_BFIN + 16 - WS_RV)   // 28688 floats

// ---------------- front-MLP recompute (per block, in LDS) ----------------
// sw[16][10] = normalized client weights; r1s[16][65] = ray hidden (padded)
__device__ __forceinline__ void front_mlp(const float* __restrict__ pref,
                                          const float* __restrict__ wm1_w,
                                          const float* __restrict__ wm1_b,
                                          const float* __restrict__ wm2_w,
                                          const float* __restrict__ wm2_b,
                                          float (*sh1)[16], float (*sw)[10],
                                          float* sinv) {
  const int t = threadIdx.x;
  {
    int r = t >> 4, j = t & 15;
    float v = pref[r * 2 + 0] * wm1_w[j * 2 + 0] + pref[r * 2 + 1] * wm1_w[j * 2 + 1] + wm1_b[j];
    sh1[r][j] = fmaxf(v, 0.f);
  }
  __syncthreads();
  if (t < 160) {
    int r = t / 10, c = t % 10;
    float z = wm2_b[c];
    for (int j = 0; j < 16; ++j) z += sh1[r][j] * wm2_w[c * 16 + j];
    sw[r][c] = 1.f / (1.f + expf(-z));
  }
  __syncthreads();
  if (t < 16) {
    float s = 0.f;
    for (int c = 0; c < 10; ++c) s += sw[t][c];
    sinv[t] = 1.f / s;
  }
  __syncthreads();
  if (t < 160) {
    int r = t / 10, c = t % 10;
    sw[r][c] = sw[r][c] * sinv[r];
  }
  __syncthreads();
}

// ---------------- S1: rv = w·(ray2_w·r1) + w·ray2_b; writes WT; W2T bias ----------------
__global__ __launch_bounds__(256) void k_stage1(
    const float* __restrict__ pref, const float* __restrict__ wm1_w,
    const float* __restrict__ wm1_b, const float* __restrict__ wm2_w,
    const float* __restrict__ wm2_b, const float* __restrict__ ray0_w,
    const float* __restrict__ ray0_b, const float* __restrict__ ray2_w,
    const float* __restrict__ ray2_b, const float* __restrict__ fc2_b,
    float* __restrict__ ws) {
  __shared__ float sh1[16][16];
  __shared__ float sw[16][10];
  __shared__ float sinv[16];
  __shared__ float r1s[16][65];
  const int t = threadIdx.x;
  front_mlp(pref, wm1_w, wm1_b, wm2_w, wm2_b, sh1, sw, sinv);
  // r1[r,o]
  for (int it = t; it < 1024; it += 256) {
    int r = it >> 6, o = it & 63;
    float m0 = 0.f, m1 = 0.f, rb = 0.f;
    for (int c = 0; c < 10; ++c) {
      float wv = sw[r][c];
      m0 += wv * ray0_w[(c * 64 + o) * 2 + 0];
      m1 += wv * ray0_w[(c * 64 + o) * 2 + 1];
      rb += wv * ray0_b[c * 64 + o];
    }
    float v = pref[r * 2 + 0] * m0 + pref[r * 2 + 1] * m1 + rb;
    r1s[r][o] = fmaxf(v, 0.f);
  }
  __syncthreads();
  // ray2_w chunk: 16 pairs per block, 16 r per pair
  const int pair = blockIdx.x * 16 + (t >> 4);
  const int r = t & 15;
  const float* row = ray2_w + (size_t)pair * 64;
  const float* r1r = r1s[r];
  float dot = 0.f;
#pragma unroll
  for (int k = 0; k < 64; ++k) dot += row[k] * r1r[k];
  int c = pair >> 7, d = pair & 127;
  atomicAdd(&ws[WS_RV + r * 128 + d], sw[r][c] * dot);

  if (blockIdx.x == 0) {
    if (t < 160) ws[WS_WT + t] = sw[t & 15][t >> 4];  // WT[c*16+r]
    for (int i = t; i < 2048; i += 256) {
      int rr = i >> 7, dd = i & 127;
      float s = 0.f;
      for (int cc = 0; cc < 10; ++cc) s += sw[rr][cc] * ray2_b[cc * 128 + dd];
      atomicAdd(&ws[WS_RV + i], s);
    }
  } else if (blockIdx.x == 1) {
    for (int i = t; i < 2048; i += 256) {
      int h = i >> 4, rr = i & 15;
      float s = 0.f;
      for (int cc = 0; cc < 10; ++cc) s += sw[rr][cc] * fc2_b[cc * 128 + h];
      atomicAdd(&ws[WS_W2T + i], s);
    }
  }
}

// ---------------- S2: W2T += w[r,c]*(fc2_w[c,h,:]·rv[r,:]) ----------------
__global__ __launch_bounds__(256) void k_stage2(const float* __restrict__ fc2_w,
                                                float* __restrict__ ws) {
  const int t = threadIdx.x;
  const int lane = t & 63;
  const int wv = blockIdx.x * 4 + (t >> 6);   // 0..319
  float2 rv2[16];
#pragma unroll
  for (int r = 0; r < 16; ++r) rv2[r] = *(const float2*)&ws[WS_RV + r * 128 + lane * 2];
  for (int q = 0; q < 4; ++q) {
    int rid = wv * 4 + q;                     // 0..1279
    int c = rid >> 7, h = rid & 127;
    float2 a = *(const float2*)&fc2_w[(size_t)rid * 128 + lane * 2];
    float u[16];
#pragma unroll
    for (int r = 0; r < 16; ++r) u[r] = a.x * rv2[r].x + a.y * rv2[r].y;
#pragma unroll
    for (int m = 1; m <= 32; m <<= 1) {
#pragma unroll
      for (int r = 0; r < 16; ++r) u[r] += __shfl_xor(u[r], m, 64);
    }
    if (lane == 0) {
#pragma unroll
      for (int r = 0; r < 16; ++r)
        atomicAdd(&ws[WS_W2T + h * 16 + r], u[r] * ws[WS_WT + c * 16 + r]);
    }
  }
}

// ---------------- K_main: fc1_w stream + fc1_b + b1 roles ----------------
__global__ __launch_bounds__(256, 3) void k_main(
    const float* __restrict__ fc1_w, const float* __restrict__ fc1_b,
    const float* __restrict__ b1_w, const float* __restrict__ b1_b,
    const float* __restrict__ b2_w, const float* __restrict__ b2_b,
    float* __restrict__ ws) {
  __shared__ float scoef[2560];        // up to 160 ch x 16 r
  __shared__ float bfred[4][16];
  const int blk = blockIdx.x;
  const int t = threadIdx.x;

  if (blk < 2048) {
    // ---- Role S: stream fc1_w (335 MB). Block = (ch-chunk of 40) x (4 fp).
    const int wid = t >> 6, lane = t & 63, l32 = lane & 31;
    const int ch0 = (blk >> 6) * 40;          // 32 chunks
    const int fp = (blk & 63) * 4 + wid;      // 0..255
    for (int i = t; i < 640; i += 256) {
      int chl = i >> 4, r = i & 15;
      int ch = ch0 + chl, c = ch >> 7, h = ch & 127;
      scoef[i] = ws[WS_WT + c * 16 + r] * ws[WS_W2T + h * 16 + r];
    }
    __syncthreads();
    float4 rv[16];
#pragma unroll
    for (int r = 0; r < 16; ++r) rv[r] = *(const float4*)&ws[WS_RV + r * 128 + l32 * 4];
    float acc[16];
#pragma unroll
    for (int r = 0; r < 16; ++r) acc[r] = 0.f;

    const float4* p = (const float4*)fc1_w + (size_t)ch0 * 16384 + fp * 64 + lane;
    float4 a0 = p[0];
    float4 a1 = p[16384];
    float4 a2 = p[2 * 16384];
    p += (size_t)3 * 16384;
    for (int chl = 0; chl < 40; ++chl) {
      float4 cur = a0; a0 = a1; a1 = a2;
      if (chl < 37) { a2 = *p; p += 16384; }
      const float4* cf = (const float4*)(scoef + chl * 16);
      float4 c0 = cf[0], c1 = cf[1], c2 = cf[2], c3 = cf[3];
      float cw[16] = {c0.x, c0.y, c0.z, c0.w, c1.x, c1.y, c1.z, c1.w,
                      c2.x, c2.y, c2.z, c2.w, c3.x, c3.y, c3.z, c3.w};
#pragma unroll
      for (int r = 0; r < 16; ++r) {
        float tt = cur.x * rv[r].x + cur.y * rv[r].y + cur.z * rv[r].z + cur.w * rv[r].w;
        acc[r] = fmaf(cw[r], tt, acc[r]);
      }
    }
#pragma unroll
    for (int m = 1; m <= 16; m <<= 1) {
#pragma unroll
      for (int r = 0; r < 16; ++r) acc[r] += __shfl_xor(acc[r], m, 64);
    }
    if (l32 == 0) {
      const int f = fp * 2 + (lane >> 5);
#pragma unroll
      for (int r = 0; r < 16; ++r) atomicAdd(&ws[WS_WEFF + r * 512 + f], acc[r]);
    }
  } else if (blk < 2064) {
    // ---- Role B1: Weff += coef * fc1_b. fc1_b flat index = ch*512 + f.
    const int bb = blk - 2048;                // 0..15
    const int f = (bb & 1) * 256 + t;
    const int ch0 = (bb >> 1) * 160;
    for (int i = t; i < 2560; i += 256) {
      int chl = i >> 4, r = i & 15;
      int ch = ch0 + chl, c = ch >> 7, h = ch & 127;
      scoef[i] = ws[WS_WT + c * 16 + r] * ws[WS_W2T + h * 16 + r];
    }
    __syncthreads();
    float acc[16];
#pragma unroll
    for (int r = 0; r < 16; ++r) acc[r] = 0.f;
    const float* q = fc1_b + (size_t)ch0 * 512 + f;
    float x0 = q[0], x1 = q[512];
    q += 1024;
    for (int it = 0; it < 160; ++it) {
      float xv = x0; x0 = x1;
      if (it < 158) { x1 = q[0]; q += 512; }
      const float4* cf = (const float4*)(scoef + it * 16);
      float4 c0 = cf[0], c1 = cf[1], c2 = cf[2], c3 = cf[3];
      float cw[16] = {c0.x, c0.y, c0.z, c0.w, c1.x, c1.y, c1.z, c1.w,
                      c2.x, c2.y, c2.z, c2.w, c3.x, c3.y, c3.z, c3.w};
#pragma unroll
      for (int r = 0; r < 16; ++r) acc[r] = fmaf(cw[r], xv, acc[r]);
    }
#pragma unroll
    for (int r = 0; r < 16; ++r) atomicAdd(&ws[WS_WEFF + r * 512 + f], acc[r]);
  } else if (blk < 2072) {
    // ---- Role H: bfin += coef * (b1_w[ch,:]·rv). b1_w flat = ch*128 + d.
    const int hb = blk - 2064;                // 0..7
    const int wid = t >> 6, lane = t & 63;
    const int ch0b = hb * 160;
    for (int i = t; i < 2560; i += 256) {
      int chl = i >> 4, r = i & 15;
      int ch = ch0b + chl, c = ch >> 7, h = ch & 127;
      scoef[i] = ws[WS_WT + c * 16 + r] * ws[WS_W2T + h * 16 + r];
    }
    __syncthreads();
    float2 rv2[16];
#pragma unroll
    for (int r = 0; r < 16; ++r) rv2[r] = *(const float2*)&ws[WS_RV + r * 128 + lane * 2];
    float acc[16];
#pragma unroll
    for (int r = 0; r < 16; ++r) acc[r] = 0.f;
    const int chl0 = wid * 40;
    const float2* q = (const float2*)b1_w + (size_t)(ch0b + chl0) * 64 + lane;
    float2 a0 = q[0], a1 = q[64];
    q += 128;
    for (int it = 0; it < 40; ++it) {
      float2 cur = a0; a0 = a1;
      if (it < 38) { a1 = q[0]; q += 64; }
      const float4* cf = (const float4*)(scoef + (chl0 + it) * 16);
      float4 c0 = cf[0], c1 = cf[1], c2 = cf[2], c3 = cf[3];
      float cw[16] = {c0.x, c0.y, c0.z, c0.w, c1.x, c1.y, c1.z, c1.w,
                      c2.x, c2.y, c2.z, c2.w, c3.x, c3.y, c3.z, c3.w};
#pragma unroll
      for (int r = 0; r < 16; ++r)
        acc[r] = fmaf(cw[r], cur.x * rv2[r].x + cur.y * rv2[r].y, acc[r]);
    }
#pragma unroll
    for (int m = 1; m <= 32; m <<= 1) {
#pragma unroll
      for (int r = 0; r < 16; ++r) acc[r] += __shfl_xor(acc[r], m, 64);
    }
    if (lane == 0) {
#pragma unroll
      for (int r = 0; r < 16; ++r) bfred[wid][r] = acc[r];
    }
    __syncthreads();
    if (t < 16)
      atomicAdd(&ws[WS_BFIN + t], bfred[0][t] + bfred[1][t] + bfred[2][t] + bfred[3][t]);
  } else {
    // ---- small terms: coef·b1_b + (w·rv)·b2_w + w·b2_b
    const int wid = t >> 6, lane = t & 63;
    float acc[16];
#pragma unroll
    for (int r = 0; r < 16; ++r) acc[r] = 0.f;
    for (int i = t; i < 1280; i += 256) {
      int c = i >> 7, h = i & 127;
      float v = b1_b[c * 128 + h];
#pragma unroll
      for (int r = 0; r < 16; ++r)
        acc[r] = fmaf(ws[WS_WT + c * 16 + r] * ws[WS_W2T + h * 16 + r], v, acc[r]);
    }
    for (int i = t; i < 1280; i += 256) {
      int c = i >> 7, d = i & 127;
      float v = b2_w[c * 128 + d];
#pragma unroll
      for (int r = 0; r < 16; ++r)
        acc[r] = fmaf(ws[WS_WT + c * 16 + r] * ws[WS_RV + r * 128 + d], v, acc[r]);
    }
    if (t < 10) {
      float v = b2_b[t];
#pragma unroll
      for (int r = 0; r < 16; ++r) acc[r] = fmaf(ws[WS_WT + t * 16 + r], v, acc[r]);
    }
#pragma unroll
    for (int m = 1; m <= 32; m <<= 1) {
#pragma unroll
      for (int r = 0; r < 16; ++r) acc[r] += __shfl_xor(acc[r], m, 64);
    }
    if (lane == 0) {
#pragma unroll
      for (int r = 0; r < 16; ++r) bfred[wid][r] = acc[r];
    }
    __syncthreads();
    if (t < 16)
      atomicAdd(&ws[WS_BFIN + t], bfred[0][t] + bfred[1][t] + bfred[2][t] + bfred[3][t]);
  }
}

// ---------------- K5: Wfin = Weff @ base_w ; bfin += Weff·base_b ----------------
__global__ __launch_bounds__(256) void k_wfin(const float* __restrict__ base_w,
                                              const float* __restrict__ base_b,
                                              float* __restrict__ ws) {
  const int t = threadIdx.x;
  const int blk = blockIdx.x;             // 128 = 4 i-tiles x 32 f-chunks
  const int i = (blk & 3) * 256 + t;
  const int f0 = (blk >> 2) * 16;
  const float* WEFF = ws + WS_WEFF;
  float acc[16];
#pragma unroll
  for (int r = 0; r < 16; ++r) acc[r] = 0.f;
#pragma unroll 4
  for (int f = f0; f < f0 + 16; ++f) {
    float bw = base_w[(size_t)f * 1024 + i];
#pragma unroll
    for (int r = 0; r < 16; ++r) acc[r] = fmaf(WEFF[r * 512 + f], bw, acc[r]);
  }
#pragma unroll
  for (int r = 0; r < 16; ++r) atomicAdd(&ws[WS_WFIN + r * 1024 + i], acc[r]);

  if (blk == 0 && t < 64) {
    float a2[16];
#pragma unroll
    for (int r = 0; r < 16; ++r) a2[r] = 0.f;
    for (int f = t; f < 512; f += 64) {
      float v = base_b[f];
#pragma unroll
      for (int r = 0; r < 16; ++r) a2[r] = fmaf(WEFF[r * 512 + f], v, a2[r]);
    }
#pragma unroll
    for (int m = 1; m <= 32; m <<= 1) {
#pragma unroll
      for (int r = 0; r < 16; ++r) a2[r] += __shfl_xor(a2[r], m, 64);
    }
    if (t == 0) {
#pragma unroll
      for (int r = 0; r < 16; ++r) atomicAdd(&ws[WS_BFIN + r], a2[r]);
    }
  }
}

// ---------------- K6: out[r,b] = x[b,:]·Wfin[r,:] + bfin[r]; sigmoid + raw ----------------
__global__ __launch_bounds__(256) void k_out(const float* __restrict__ x,
                                             const float* __restrict__ ws,
                                             float* __restrict__ out) {
  __shared__ float4 wfs[4096];            // 64 KB: Wfin as [r*256 + i4]
  const int t = threadIdx.x;
  const float4* wf4 = (const float4*)(ws + WS_WFIN);
#pragma unroll
  for (int k = 0; k < 16; ++k) wfs[t + 256 * k] = wf4[t + 256 * k];
  __syncthreads();

  const int b0 = blockIdx.x * 16;
  const int bp = t >> 5;                  // 0..7 (b-pair)
  const int isub = t & 31;
  const int bA = b0 + bp * 2;
  const float* xa = x + (size_t)bA * 1024;
  const float* xb = xa + 1024;
  float acc0[16], acc1[16];
#pragma unroll
  for (int r = 0; r < 16; ++r) { acc0[r] = 0.f; acc1[r] = 0.f; }

  for (int chunk = 0; chunk < 4; ++chunk) {
#pragma unroll
    for (int j = 0; j < 2; ++j) {
      const int off = chunk * 256 + j * 128 + isub * 4;
      float4 xv0 = *(const float4*)&xa[off];
      float4 xv1 = *(const float4*)&xb[off];
      const float4* wrow = wfs + chunk * 64 + j * 32 + isub;
#pragma unroll
      for (int r = 0; r < 16; ++r) {
        float4 w = wrow[r * 256];
        acc0[r] += xv0.x * w.x + xv0.y * w.y + xv0.z * w.z + xv0.w * w.w;
        acc1[r] += xv1.x * w.x + xv1.y * w.y + xv1.z * w.z + xv1.w * w.w;
      }
    }
  }
#pragma unroll
  for (int m = 1; m <= 16; m <<= 1) {
#pragma unroll
    for (int r = 0; r < 16; ++r) {
      acc0[r] += __shfl_xor(acc0[r], m, 64);
      acc1[r] += __shfl_xor(acc1[r], m, 64);
    }
  }
  if (isub == 0) {
#pragma unroll
    for (int r = 0; r < 16; ++r) {
      float bf = ws[WS_BFIN + r];
      float v0 = acc0[r] + bf;
      float v1 = acc1[r] + bf;
      out[r * 4096 + bA] = 1.f / (1.f + expf(-v0));
      out[r * 4096 + bA + 1] = 1.f / (1.f + expf(-v1));
      out[65536 + r * 4096 + bA] = v0;
      out[65536 + r * 4096 + bA + 1] = v1;
    }
  }
}

extern "C" void kernel_launch(void* const* d_in, const int* in_sizes, int n_in,
                              void* d_out, int out_size, void* d_ws, size_t ws_size,
                              hipStream_t stream) {
  (void)in_sizes; (void)n_in; (void)out_size; (void)ws_size;
  const float* x      = (const float*)d_in[0];
  const float* pref   = (const float*)d_in[1];
  const float* base_w = (const float*)d_in[2];
  const float* base_b = (const float*)d_in[3];
  const float* wm1_w  = (const float*)d_in[4];
  const float* wm1_b  = (const float*)d_in[5];
  const float* wm2_w  = (const float*)d_in[6];
  const float* wm2_b  = (const float*)d_in[7];
  const float* ray0_w = (const float*)d_in[8];
  const float* ray0_b = (const float*)d_in[9];
  const float* ray2_w = (const float*)d_in[10];
  const float* ray2_b = (const float*)d_in[11];
  const float* fc1_w  = (const float*)d_in[12];
  const float* fc1_b  = (const float*)d_in[13];
  const float* b1_w   = (const float*)d_in[14];
  const float* b1_b   = (const float*)d_in[15];
  const float* fc2_w  = (const float*)d_in[16];
  const float* fc2_b  = (const float*)d_in[17];
  const float* b2_w   = (const float*)d_in[18];
  const float* b2_b   = (const float*)d_in[19];
  float* ws  = (float*)d_ws;
  float* out = (float*)d_out;

  hipMemsetAsync(ws + WS_ZERO_BEG, 0, (size_t)WS_ZERO_CNT * sizeof(float), stream);
  k_stage1<<<80, 256, 0, stream>>>(pref, wm1_w, wm1_b, wm2_w, wm2_b,
                                   ray0_w, ray0_b, ray2_w, ray2_b, fc2_b, ws);
  k_stage2<<<80, 256, 0, stream>>>(fc2_w, ws);
  k_main<<<2073, 256, 0, stream>>>(fc1_w, fc1_b, b1_w, b1_b, b2_w, b2_b, ws);
  k_wfin<<<128, 256, 0, stream>>>(base_w, base_b, ws);
  k_out<<<256, 256, 0, stream>>>(x, ws, out);
}

// Round 3
// 565.745 us; speedup vs baseline: 1.1509x; 1.0011x over previous
//
#include <hip/hip_runtime.h>
#include <cstddef>
#include <cstdint>

// B=4096, IN=1024, F=512, HID=128, D=128, RH=64, OUT=1, C=10, R=16
//
// out[r,b] = x[b,:]·Wfin[r,:] + bfin[r]
//   Weff[r,f] = sum_{c,h,d} w[r,c] W2[r,h] rv[r,d] fc1_w[c,h*512+f,d]
//             + sum_{c,h}   w[r,c] W2[r,h] fc1_b[c,h*512+f]
//   Wfin[r,i] = sum_f Weff[r,f] base_w[f,i]
//   bfin[r]   = sum_f Weff[r,f] base_b[f] + b1/b2 terms via hyper linearity

// ws float offsets
#define WS_WT    0        // 160    wT[c*16+r]
#define WS_RV    160      // 2048   rv[r*128+d]
#define WS_W2T   2208     // 2048   W2T[h*16+r]
#define WS_WEFF  4256     // 8192   Weff[r*512+f]
#define WS_WFIN  12448    // 16384  Wfin[r*1024+i]
#define WS_BFIN  28832    // 16
#define WS_ZERO_BEG WS_RV
#define WS_ZERO_CNT (WS_BFIN + 16 - WS_RV)   // 28688 floats

// async global->LDS, 16 bytes per lane (global_load_lds_dwordx4).
// lds dest is wave-uniform base; data lands at base + lane*16.
__device__ __forceinline__ void async_ld16(const float* g, float* l) {
  __builtin_amdgcn_global_load_lds(
      (const __attribute__((address_space(1))) uint32_t*)g,
      (__attribute__((address_space(3))) uint32_t*)l, 16, 0, 0);
}

// ---------------- front-MLP recompute (per block, in LDS) ----------------
__device__ __forceinline__ void front_mlp(const float* __restrict__ pref,
                                          const float* __restrict__ wm1_w,
                                          const float* __restrict__ wm1_b,
                                          const float* __restrict__ wm2_w,
                                          const float* __restrict__ wm2_b,
                                          float (*sh1)[16], float (*sw)[10],
                                          float* sinv) {
  const int t = threadIdx.x;
  {
    int r = t >> 4, j = t & 15;
    float v = pref[r * 2 + 0] * wm1_w[j * 2 + 0] + pref[r * 2 + 1] * wm1_w[j * 2 + 1] + wm1_b[j];
    sh1[r][j] = fmaxf(v, 0.f);
  }
  __syncthreads();
  if (t < 160) {
    int r = t / 10, c = t % 10;
    float z = wm2_b[c];
    for (int j = 0; j < 16; ++j) z += sh1[r][j] * wm2_w[c * 16 + j];
    sw[r][c] = 1.f / (1.f + expf(-z));
  }
  __syncthreads();
  if (t < 16) {
    float s = 0.f;
    for (int c = 0; c < 10; ++c) s += sw[t][c];
    sinv[t] = 1.f / s;
  }
  __syncthreads();
  if (t < 160) {
    int r = t / 10, c = t % 10;
    sw[r][c] = sw[r][c] * sinv[r];
  }
  __syncthreads();
}

// ---------------- S1: rv = w·(ray2_w·r1) + w·ray2_b; writes WT; W2T bias ----------------
__global__ __launch_bounds__(256) void k_stage1(
    const float* __restrict__ pref, const float* __restrict__ wm1_w,
    const float* __restrict__ wm1_b, const float* __restrict__ wm2_w,
    const float* __restrict__ wm2_b, const float* __restrict__ ray0_w,
    const float* __restrict__ ray0_b, const float* __restrict__ ray2_w,
    const float* __restrict__ ray2_b, const float* __restrict__ fc2_b,
    float* __restrict__ ws) {
  __shared__ float sh1[16][16];
  __shared__ float sw[16][10];
  __shared__ float sinv[16];
  __shared__ float r1s[16][65];
  const int t = threadIdx.x;
  front_mlp(pref, wm1_w, wm1_b, wm2_w, wm2_b, sh1, sw, sinv);
  for (int it = t; it < 1024; it += 256) {
    int r = it >> 6, o = it & 63;
    float m0 = 0.f, m1 = 0.f, rb = 0.f;
    for (int c = 0; c < 10; ++c) {
      float wv = sw[r][c];
      m0 += wv * ray0_w[(c * 64 + o) * 2 + 0];
      m1 += wv * ray0_w[(c * 64 + o) * 2 + 1];
      rb += wv * ray0_b[c * 64 + o];
    }
    float v = pref[r * 2 + 0] * m0 + pref[r * 2 + 1] * m1 + rb;
    r1s[r][o] = fmaxf(v, 0.f);
  }
  __syncthreads();
  const int pair = blockIdx.x * 16 + (t >> 4);
  const int r = t & 15;
  const float* row = ray2_w + (size_t)pair * 64;
  const float* r1r = r1s[r];
  float dot = 0.f;
#pragma unroll
  for (int k = 0; k < 64; ++k) dot += row[k] * r1r[k];
  int c = pair >> 7, d = pair & 127;
  atomicAdd(&ws[WS_RV + r * 128 + d], sw[r][c] * dot);

  if (blockIdx.x == 0) {
    if (t < 160) ws[WS_WT + t] = sw[t & 15][t >> 4];  // WT[c*16+r]
    for (int i = t; i < 2048; i += 256) {
      int rr = i >> 7, dd = i & 127;
      float s = 0.f;
      for (int cc = 0; cc < 10; ++cc) s += sw[rr][cc] * ray2_b[cc * 128 + dd];
      atomicAdd(&ws[WS_RV + i], s);
    }
  } else if (blockIdx.x == 1) {
    for (int i = t; i < 2048; i += 256) {
      int h = i >> 4, rr = i & 15;
      float s = 0.f;
      for (int cc = 0; cc < 10; ++cc) s += sw[rr][cc] * fc2_b[cc * 128 + h];
      atomicAdd(&ws[WS_W2T + i], s);
    }
  }
}

// ---------------- S2: W2T += w[r,c]*(fc2_w[c,h,:]·rv[r,:]) ----------------
__global__ __launch_bounds__(256) void k_stage2(const float* __restrict__ fc2_w,
                                                float* __restrict__ ws) {
  const int t = threadIdx.x;
  const int lane = t & 63;
  const int wv = blockIdx.x * 4 + (t >> 6);   // 0..319
  float2 rv2[16];
#pragma unroll
  for (int r = 0; r < 16; ++r) rv2[r] = *(const float2*)&ws[WS_RV + r * 128 + lane * 2];
  for (int q = 0; q < 4; ++q) {
    int rid = wv * 4 + q;                     // 0..1279
    int c = rid >> 7, h = rid & 127;
    float2 a = *(const float2*)&fc2_w[(size_t)rid * 128 + lane * 2];
    float u[16];
#pragma unroll
    for (int r = 0; r < 16; ++r) u[r] = a.x * rv2[r].x + a.y * rv2[r].y;
#pragma unroll
    for (int m = 1; m <= 32; m <<= 1) {
#pragma unroll
      for (int r = 0; r < 16; ++r) u[r] += __shfl_xor(u[r], m, 64);
    }
    if (lane == 0) {
#pragma unroll
      for (int r = 0; r < 16; ++r)
        atomicAdd(&ws[WS_W2T + h * 16 + r], u[r] * ws[WS_WT + c * 16 + r]);
    }
  }
}

// ---------------- K_main: fc1_w stream (async LDS ring) + fc1_b + b1 roles ----------------
__global__ __launch_bounds__(256, 3) void k_main(
    const float* __restrict__ fc1_w, const float* __restrict__ fc1_b,
    const float* __restrict__ b1_w, const float* __restrict__ b1_b,
    const float* __restrict__ b2_w, const float* __restrict__ b2_b,
    float* __restrict__ ws) {
  __shared__ float ring[4][8 * 256];   // 4 waves x 8 slots x 1KB = 32 KB
  __shared__ float scoef[2560];        // up to 160 ch x 16 r
  __shared__ float bfred[4][16];
  const int blk = blockIdx.x;
  const int t = threadIdx.x;

  if (blk < 2048) {
    // ---- Role S: stream fc1_w (335 MB). Block = (ch-chunk of 40) x (4 fp).
    const int wid = t >> 6, lane = t & 63, l32 = lane & 31;
    const int ch0 = (blk >> 6) * 40;          // 32 chunks of 40 ch
    const int fp = (blk & 63) * 4 + wid;      // 0..255 (f-pair)
    for (int i = t; i < 640; i += 256) {
      int chl = i >> 4, r = i & 15;
      int ch = ch0 + chl, c = ch >> 7, h = ch & 127;
      scoef[i] = ws[WS_WT + c * 16 + r] * ws[WS_W2T + h * 16 + r];
    }
    float4 rv[16];
#pragma unroll
    for (int r = 0; r < 16; ++r) rv[r] = *(const float4*)&ws[WS_RV + r * 128 + l32 * 4];
    __syncthreads();   // drains vm+lgkm; after this, vmcnt==0 for this wave

    float* myring = &ring[wid][0];
    // per-lane global addr for chunk j: fc1_w + (ch0+j)*65536 + fp*256 + lane*4
    const float* gb = fc1_w + (size_t)ch0 * 65536 + fp * 256 + lane * 4;
    float acc[16];
#pragma unroll
    for (int r = 0; r < 16; ++r) acc[r] = 0.f;

    // prologue: 6 outstanding
#pragma unroll
    for (int j = 0; j < 6; ++j)
      async_ld16(gb + (size_t)j * 65536, myring + j * 256);

    int chl = 0;
    for (; chl < 34; ++chl) {
      asm volatile("s_waitcnt vmcnt(5)" ::: "memory");
      const float4 dv = *(const float4*)(myring + (chl & 7) * 256 + lane * 4);
      const float4* cf = (const float4*)(scoef + chl * 16);
      float4 c0 = cf[0], c1 = cf[1], c2 = cf[2], c3 = cf[3];
      float cw[16] = {c0.x, c0.y, c0.z, c0.w, c1.x, c1.y, c1.z, c1.w,
                      c2.x, c2.y, c2.z, c2.w, c3.x, c3.y, c3.z, c3.w};
#pragma unroll
      for (int r = 0; r < 16; ++r) {
        float tt = dv.x * rv[r].x + dv.y * rv[r].y + dv.z * rv[r].z + dv.w * rv[r].w;
        acc[r] = fmaf(cw[r], tt, acc[r]);
      }
      async_ld16(gb + (size_t)(chl + 6) * 65536, myring + ((chl + 6) & 7) * 256);
    }
    asm volatile("s_waitcnt vmcnt(0)" ::: "memory");
    for (; chl < 40; ++chl) {
      const float4 dv = *(const float4*)(myring + (chl & 7) * 256 + lane * 4);
      const float4* cf = (const float4*)(scoef + chl * 16);
      float4 c0 = cf[0], c1 = cf[1], c2 = cf[2], c3 = cf[3];
      float cw[16] = {c0.x, c0.y, c0.z, c0.w, c1.x, c1.y, c1.z, c1.w,
                      c2.x, c2.y, c2.z, c2.w, c3.x, c3.y, c3.z, c3.w};
#pragma unroll
      for (int r = 0; r < 16; ++r) {
        float tt = dv.x * rv[r].x + dv.y * rv[r].y + dv.z * rv[r].z + dv.w * rv[r].w;
        acc[r] = fmaf(cw[r], tt, acc[r]);
      }
    }

#pragma unroll
    for (int m = 1; m <= 16; m <<= 1) {
#pragma unroll
      for (int r = 0; r < 16; ++r) acc[r] += __shfl_xor(acc[r], m, 64);
    }
    if (l32 == 0) {
      const int f = fp * 2 + (lane >> 5);
#pragma unroll
      for (int r = 0; r < 16; ++r) atomicAdd(&ws[WS_WEFF + r * 512 + f], acc[r]);
    }
  } else if (blk < 2064) {
    // ---- Role B1: Weff += coef * fc1_b. fc1_b flat index = ch*512 + f.
    const int bb = blk - 2048;                // 0..15
    const int f = (bb & 1) * 256 + t;
    const int ch0 = (bb >> 1) * 160;
    for (int i = t; i < 2560; i += 256) {
      int chl = i >> 4, r = i & 15;
      int ch = ch0 + chl, c = ch >> 7, h = ch & 127;
      scoef[i] = ws[WS_WT + c * 16 + r] * ws[WS_W2T + h * 16 + r];
    }
    __syncthreads();
    float acc[16];
#pragma unroll
    for (int r = 0; r < 16; ++r) acc[r] = 0.f;
    const float* q = fc1_b + (size_t)ch0 * 512 + f;
    float x0 = q[0], x1 = q[512];
    q += 1024;
    for (int it = 0; it < 160; ++it) {
      float xv = x0; x0 = x1;
      if (it < 158) { x1 = q[0]; q += 512; }
      const float4* cf = (const float4*)(scoef + it * 16);
      float4 c0 = cf[0], c1 = cf[1], c2 = cf[2], c3 = cf[3];
      float cw[16] = {c0.x, c0.y, c0.z, c0.w, c1.x, c1.y, c1.z, c1.w,
                      c2.x, c2.y, c2.z, c2.w, c3.x, c3.y, c3.z, c3.w};
#pragma unroll
      for (int r = 0; r < 16; ++r) acc[r] = fmaf(cw[r], xv, acc[r]);
    }
#pragma unroll
    for (int r = 0; r < 16; ++r) atomicAdd(&ws[WS_WEFF + r * 512 + f], acc[r]);
  } else if (blk < 2072) {
    // ---- Role H: bfin += coef * (b1_w[ch,:]·rv). b1_w flat = ch*128 + d.
    const int hb = blk - 2064;                // 0..7
    const int wid = t >> 6, lane = t & 63;
    const int ch0b = hb * 160;
    for (int i = t; i < 2560; i += 256) {
      int chl = i >> 4, r = i & 15;
      int ch = ch0b + chl, c = ch >> 7, h = ch & 127;
      scoef[i] = ws[WS_WT + c * 16 + r] * ws[WS_W2T + h * 16 + r];
    }
    __syncthreads();
    float2 rv2[16];
#pragma unroll
    for (int r = 0; r < 16; ++r) rv2[r] = *(const float2*)&ws[WS_RV + r * 128 + lane * 2];
    float acc[16];
#pragma unroll
    for (int r = 0; r < 16; ++r) acc[r] = 0.f;
    const int chl0 = wid * 40;
    const float2* q = (const float2*)b1_w + (size_t)(ch0b + chl0) * 64 + lane;
    float2 a0 = q[0], a1 = q[64];
    q += 128;
    for (int it = 0; it < 40; ++it) {
      float2 cur = a0; a0 = a1;
      if (it < 38) { a1 = q[0]; q += 64; }
      const float4* cf = (const float4*)(scoef + (chl0 + it) * 16);
      float4 c0 = cf[0], c1 = cf[1], c2 = cf[2], c3 = cf[3];
      float cw[16] = {c0.x, c0.y, c0.z, c0.w, c1.x, c1.y, c1.z, c1.w,
                      c2.x, c2.y, c2.z, c2.w, c3.x, c3.y, c3.z, c3.w};
#pragma unroll
      for (int r = 0; r < 16; ++r)
        acc[r] = fmaf(cw[r], cur.x * rv2[r].x + cur.y * rv2[r].y, acc[r]);
    }
#pragma unroll
    for (int m = 1; m <= 32; m <<= 1) {
#pragma unroll
      for (int r = 0; r < 16; ++r) acc[r] += __shfl_xor(acc[r], m, 64);
    }
    if (lane == 0) {
#pragma unroll
      for (int r = 0; r < 16; ++r) bfred[wid][r] = acc[r];
    }
    __syncthreads();
    if (t < 16)
      atomicAdd(&ws[WS_BFIN + t], bfred[0][t] + bfred[1][t] + bfred[2][t] + bfred[3][t]);
  } else {
    // ---- small terms: coef·b1_b + (w·rv)·b2_w + w·b2_b
    const int wid = t >> 6, lane = t & 63;
    float acc[16];
#pragma unroll
    for (int r = 0; r < 16; ++r) acc[r] = 0.f;
    for (int i = t; i < 1280; i += 256) {
      int c = i >> 7, h = i & 127;
      float v = b1_b[c * 128 + h];
#pragma unroll
      for (int r = 0; r < 16; ++r)
        acc[r] = fmaf(ws[WS_WT + c * 16 + r] * ws[WS_W2T + h * 16 + r], v, acc[r]);
    }
    for (int i = t; i < 1280; i += 256) {
      int c = i >> 7, d = i & 127;
      float v = b2_w[c * 128 + d];
#pragma unroll
      for (int r = 0; r < 16; ++r)
        acc[r] = fmaf(ws[WS_WT + c * 16 + r] * ws[WS_RV + r * 128 + d], v, acc[r]);
    }
    if (t < 10) {
      float v = b2_b[t];
#pragma unroll
      for (int r = 0; r < 16; ++r) acc[r] = fmaf(ws[WS_WT + t * 16 + r], v, acc[r]);
    }
#pragma unroll
    for (int m = 1; m <= 32; m <<= 1) {
#pragma unroll
      for (int r = 0; r < 16; ++r) acc[r] += __shfl_xor(acc[r], m, 64);
    }
    if (lane == 0) {
#pragma unroll
      for (int r = 0; r < 16; ++r) bfred[wid][r] = acc[r];
    }
    __syncthreads();
    if (t < 16)
      atomicAdd(&ws[WS_BFIN + t], bfred[0][t] + bfred[1][t] + bfred[2][t] + bfred[3][t]);
  }
}

// ---------------- K5: Wfin = Weff @ base_w ; bfin += Weff·base_b ----------------
__global__ __launch_bounds__(256) void k_wfin(const float* __restrict__ base_w,
                                              const float* __restrict__ base_b,
                                              float* __restrict__ ws) {
  const int t = threadIdx.x;
  const int blk = blockIdx.x;             // 128 = 4 i-tiles x 32 f-chunks
  const int i = (blk & 3) * 256 + t;
  const int f0 = (blk >> 2) * 16;
  const float* WEFF = ws + WS_WEFF;
  float acc[16];
#pragma unroll
  for (int r = 0; r < 16; ++r) acc[r] = 0.f;
#pragma unroll 4
  for (int f = f0; f < f0 + 16; ++f) {
    float bw = base_w[(size_t)f * 1024 + i];
#pragma unroll
    for (int r = 0; r < 16; ++r) acc[r] = fmaf(WEFF[r * 512 + f], bw, acc[r]);
  }
#pragma unroll
  for (int r = 0; r < 16; ++r) atomicAdd(&ws[WS_WFIN + r * 1024 + i], acc[r]);

  if (blk == 0 && t < 64) {
    float a2[16];
#pragma unroll
    for (int r = 0; r < 16; ++r) a2[r] = 0.f;
    for (int f = t; f < 512; f += 64) {
      float v = base_b[f];
#pragma unroll
      for (int r = 0; r < 16; ++r) a2[r] = fmaf(WEFF[r * 512 + f], v, a2[r]);
    }
#pragma unroll
    for (int m = 1; m <= 32; m <<= 1) {
#pragma unroll
      for (int r = 0; r < 16; ++r) a2[r] += __shfl_xor(a2[r], m, 64);
    }
    if (t == 0) {
#pragma unroll
      for (int r = 0; r < 16; ++r) atomicAdd(&ws[WS_BFIN + r], a2[r]);
    }
  }
}

// ---------------- K6: out[r,b] = x[b,:]·Wfin[r,:] + bfin[r]; sigmoid + raw ----------------
__global__ __launch_bounds__(256) void k_out(const float* __restrict__ x,
                                             const float* __restrict__ ws,
                                             float* __restrict__ out) {
  __shared__ float4 wfs[4096];            // 64 KB: Wfin as [r*256 + i4]
  const int t = threadIdx.x;
  const float4* wf4 = (const float4*)(ws + WS_WFIN);
#pragma unroll
  for (int k = 0; k < 16; ++k) wfs[t + 256 * k] = wf4[t + 256 * k];
  __syncthreads();

  const int b0 = blockIdx.x * 16;
  const int bp = t >> 5;                  // 0..7 (b-pair)
  const int isub = t & 31;
  const int bA = b0 + bp * 2;
  const float* xa = x + (size_t)bA * 1024;
  const float* xb = xa + 1024;
  float acc0[16], acc1[16];
#pragma unroll
  for (int r = 0; r < 16; ++r) { acc0[r] = 0.f; acc1[r] = 0.f; }

  for (int chunk = 0; chunk < 4; ++chunk) {
#pragma unroll
    for (int j = 0; j < 2; ++j) {
      const int off = chunk * 256 + j * 128 + isub * 4;
      float4 xv0 = *(const float4*)&xa[off];
      float4 xv1 = *(const float4*)&xb[off];
      const float4* wrow = wfs + chunk * 64 + j * 32 + isub;
#pragma unroll
      for (int r = 0; r < 16; ++r) {
        float4 w = wrow[r * 256];
        acc0[r] += xv0.x * w.x + xv0.y * w.y + xv0.z * w.z + xv0.w * w.w;
        acc1[r] += xv1.x * w.x + xv1.y * w.y + xv1.z * w.z + xv1.w * w.w;
      }
    }
  }
#pragma unroll
  for (int m = 1; m <= 16; m <<= 1) {
#pragma unroll
    for (int r = 0; r < 16; ++r) {
      acc0[r] += __shfl_xor(acc0[r], m, 64);
      acc1[r] += __shfl_xor(acc1[r], m, 64);
    }
  }
  if (isub == 0) {
#pragma unroll
    for (int r = 0; r < 16; ++r) {
      float bf = ws[WS_BFIN + r];
      float v0 = acc0[r] + bf;
      float v1 = acc1[r] + bf;
      out[r * 4096 + bA] = 1.f / (1.f + expf(-v0));
      out[r * 4096 + bA + 1] = 1.f / (1.f + expf(-v1));
      out[65536 + r * 4096 + bA] = v0;
      out[65536 + r * 4096 + bA + 1] = v1;
    }
  }
}

extern "C" void kernel_launch(void* const* d_in, const int* in_sizes, int n_in,
                              void* d_out, int out_size, void* d_ws, size_t ws_size,
                              hipStream_t stream) {
  (void)in_sizes; (void)n_in; (void)out_size; (void)ws_size;
  const float* x      = (const float*)d_in[0];
  const float* pref   = (const float*)d_in[1];
  const float* base_w = (const float*)d_in[2];
  const float* base_b = (const float*)d_in[3];
  const float* wm1_w  = (const float*)d_in[4];
  const float* wm1_b  = (const float*)d_in[5];
  const float* wm2_w  = (const float*)d_in[6];
  const float* wm2_b  = (const float*)d_in[7];
  const float* ray0_w = (const float*)d_in[8];
  const float* ray0_b = (const float*)d_in[9];
  const float* ray2_w = (const float*)d_in[10];
  const float* ray2_b = (const float*)d_in[11];
  const float* fc1_w  = (const float*)d_in[12];
  const float* fc1_b  = (const float*)d_in[13];
  const float* b1_w   = (const float*)d_in[14];
  const float* b1_b   = (const float*)d_in[15];
  const float* fc2_w  = (const float*)d_in[16];
  const float* fc2_b  = (const float*)d_in[17];
  const float* b2_w   = (const float*)d_in[18];
  const float* b2_b   = (const float*)d_in[19];
  float* ws  = (float*)d_ws;
  float* out = (float*)d_out;

  hipMemsetAsync(ws + WS_ZERO_BEG, 0, (size_t)WS_ZERO_CNT * sizeof(float), stream);
  k_stage1<<<80, 256, 0, stream>>>(pref, wm1_w, wm1_b, wm2_w, wm2_b,
                                   ray0_w, ray0_b, ray2_w, ray2_b, fc2_b, ws);
  k_stage2<<<80, 256, 0, stream>>>(fc2_w, ws);
  k_main<<<2073, 256, 0, stream>>>(fc1_w, fc1_b, b1_w, b1_b, b2_w, b2_b, ws);
  k_wfin<<<128, 256, 0, stream>>>(base_w, base_b, ws);
  k_out<<<256, 256, 0, stream>>>(x, ws, out);
}

// Round 4
// 559.577 us; speedup vs baseline: 1.1636x; 1.0110x over previous
//
#include <hip/hip_runtime.h>
#include <cstddef>
#include <cstdint>

// B=4096, IN=1024, F=512, HID=128, D=128, RH=64, OUT=1, C=10, R=16
//
// out[r,b] = x[b,:]·Wfin[r,:] + bfin[r]
//   Weff[r,f] = sum_{c,h,d} w[r,c] W2[r,h] rv[r,d] fc1_w[c,h*512+f,d]
//             + sum_{c,h}   w[r,c] W2[r,h] fc1_b[c,h*512+f]
//   Wfin[r,i] = sum_f Weff[r,f] base_w[f,i]
//   bfin[r]   = sum_f Weff[r,f] base_b[f] + b1/b2 terms via hyper linearity

// ws float offsets
#define WS_WT    0        // 160    wT[c*16+r]
#define WS_RV    160      // 2048   rv[r*128+d]
#define WS_W2T   2208     // 2048   W2T[h*16+r]
#define WS_WEFF  4256     // 8192   Weff[r*512+f]
#define WS_WFIN  12448    // 16384  Wfin[r*1024+i]
#define WS_BFIN  28832    // 16
#define WS_ZERO_BEG WS_RV
#define WS_ZERO_CNT (WS_BFIN + 16 - WS_RV)   // 28688 floats

// ---------------- front-MLP recompute (per block, in LDS) ----------------
__device__ __forceinline__ void front_mlp(const float* __restrict__ pref,
                                          const float* __restrict__ wm1_w,
                                          const float* __restrict__ wm1_b,
                                          const float* __restrict__ wm2_w,
                                          const float* __restrict__ wm2_b,
                                          float (*sh1)[16], float (*sw)[10],
                                          float* sinv) {
  const int t = threadIdx.x;
  {
    int r = t >> 4, j = t & 15;
    float v = pref[r * 2 + 0] * wm1_w[j * 2 + 0] + pref[r * 2 + 1] * wm1_w[j * 2 + 1] + wm1_b[j];
    sh1[r][j] = fmaxf(v, 0.f);
  }
  __syncthreads();
  if (t < 160) {
    int r = t / 10, c = t % 10;
    float z = wm2_b[c];
    for (int j = 0; j < 16; ++j) z += sh1[r][j] * wm2_w[c * 16 + j];
    sw[r][c] = 1.f / (1.f + expf(-z));
  }
  __syncthreads();
  if (t < 16) {
    float s = 0.f;
    for (int c = 0; c < 10; ++c) s += sw[t][c];
    sinv[t] = 1.f / s;
  }
  __syncthreads();
  if (t < 160) {
    int r = t / 10, c = t % 10;
    sw[r][c] = sw[r][c] * sinv[r];
  }
  __syncthreads();
}

// ---------------- S1: rv = w·(ray2_w·r1) + w·ray2_b; writes WT; W2T bias ----------------
__global__ __launch_bounds__(256) void k_stage1(
    const float* __restrict__ pref, const float* __restrict__ wm1_w,
    const float* __restrict__ wm1_b, const float* __restrict__ wm2_w,
    const float* __restrict__ wm2_b, const float* __restrict__ ray0_w,
    const float* __restrict__ ray0_b, const float* __restrict__ ray2_w,
    const float* __restrict__ ray2_b, const float* __restrict__ fc2_b,
    float* __restrict__ ws) {
  __shared__ float sh1[16][16];
  __shared__ float sw[16][10];
  __shared__ float sinv[16];
  __shared__ float r1s[16][65];
  const int t = threadIdx.x;
  front_mlp(pref, wm1_w, wm1_b, wm2_w, wm2_b, sh1, sw, sinv);
  for (int it = t; it < 1024; it += 256) {
    int r = it >> 6, o = it & 63;
    float m0 = 0.f, m1 = 0.f, rb = 0.f;
    for (int c = 0; c < 10; ++c) {
      float wv = sw[r][c];
      m0 += wv * ray0_w[(c * 64 + o) * 2 + 0];
      m1 += wv * ray0_w[(c * 64 + o) * 2 + 1];
      rb += wv * ray0_b[c * 64 + o];
    }
    float v = pref[r * 2 + 0] * m0 + pref[r * 2 + 1] * m1 + rb;
    r1s[r][o] = fmaxf(v, 0.f);
  }
  __syncthreads();
  const int pair = blockIdx.x * 16 + (t >> 4);
  const int r = t & 15;
  const float* row = ray2_w + (size_t)pair * 64;
  const float* r1r = r1s[r];
  float dot = 0.f;
#pragma unroll
  for (int k = 0; k < 64; ++k) dot += row[k] * r1r[k];
  int c = pair >> 7, d = pair & 127;
  atomicAdd(&ws[WS_RV + r * 128 + d], sw[r][c] * dot);

  if (blockIdx.x == 0) {
    if (t < 160) ws[WS_WT + t] = sw[t & 15][t >> 4];  // WT[c*16+r]
    for (int i = t; i < 2048; i += 256) {
      int rr = i >> 7, dd = i & 127;
      float s = 0.f;
      for (int cc = 0; cc < 10; ++cc) s += sw[rr][cc] * ray2_b[cc * 128 + dd];
      atomicAdd(&ws[WS_RV + i], s);
    }
  } else if (blockIdx.x == 1) {
    for (int i = t; i < 2048; i += 256) {
      int h = i >> 4, rr = i & 15;
      float s = 0.f;
      for (int cc = 0; cc < 10; ++cc) s += sw[rr][cc] * fc2_b[cc * 128 + h];
      atomicAdd(&ws[WS_W2T + i], s);
    }
  }
}

// ---------------- S2: W2T += w[r,c]*(fc2_w[c,h,:]·rv[r,:]) ----------------
__global__ __launch_bounds__(256) void k_stage2(const float* __restrict__ fc2_w,
                                                float* __restrict__ ws) {
  const int t = threadIdx.x;
  const int lane = t & 63;
  const int wv = blockIdx.x * 4 + (t >> 6);   // 0..319
  float2 rv2[16];
#pragma unroll
  for (int r = 0; r < 16; ++r) rv2[r] = *(const float2*)&ws[WS_RV + r * 128 + lane * 2];
  for (int q = 0; q < 4; ++q) {
    int rid = wv * 4 + q;                     // 0..1279
    int c = rid >> 7, h = rid & 127;
    float2 a = *(const float2*)&fc2_w[(size_t)rid * 128 + lane * 2];
    float u[16];
#pragma unroll
    for (int r = 0; r < 16; ++r) u[r] = a.x * rv2[r].x + a.y * rv2[r].y;
#pragma unroll
    for (int m = 1; m <= 32; m <<= 1) {
#pragma unroll
      for (int r = 0; r < 16; ++r) u[r] += __shfl_xor(u[r], m, 64);
    }
    if (lane == 0) {
#pragma unroll
      for (int r = 0; r < 16; ++r)
        atomicAdd(&ws[WS_W2T + h * 16 + r], u[r] * ws[WS_WT + c * 16 + r]);
    }
  }
}

// ---------------- K_main: fc1_w stream (depth-8 VGPR pipeline) + fc1_b + b1 roles ----------------
__global__ __launch_bounds__(256, 3) void k_main(
    const float* __restrict__ fc1_w, const float* __restrict__ fc1_b,
    const float* __restrict__ b1_w, const float* __restrict__ b1_b,
    const float* __restrict__ b2_w, const float* __restrict__ b2_b,
    float* __restrict__ ws) {
  __shared__ float scoef[2560];        // up to 160 ch x 16 r
  __shared__ float bfred[4][16];
  const int blk = blockIdx.x;
  const int t = threadIdx.x;

  if (blk < 2048) {
    // ---- Role S: stream fc1_w (335 MB). Block = (ch-chunk of 40) x (4 fp).
    const int wid = t >> 6, lane = t & 63, l32 = lane & 31;
    const int ch0 = (blk >> 6) * 40;          // 32 chunks of 40 ch
    const int fp = (blk & 63) * 4 + wid;      // 0..255 (f-pair)
    for (int i = t; i < 640; i += 256) {
      int chl = i >> 4, r = i & 15;
      int ch = ch0 + chl, c = ch >> 7, h = ch & 127;
      scoef[i] = ws[WS_WT + c * 16 + r] * ws[WS_W2T + h * 16 + r];
    }
    float4 rv[16];
#pragma unroll
    for (int r = 0; r < 16; ++r) rv[r] = *(const float4*)&ws[WS_RV + r * 128 + l32 * 4];
    __syncthreads();

    float acc[16];
#pragma unroll
    for (int r = 0; r < 16; ++r) acc[r] = 0.f;

    // per-lane stream base; iteration chl reads p[chl*16384] (float4 units)
    const float4* p = (const float4*)fc1_w + (size_t)ch0 * 16384 + fp * 64 + lane;

    // depth-8 register pipeline, all loads unconditional (tail clamped to 39)
    float4 buf[8];
#pragma unroll
    for (int j = 0; j < 8; ++j) buf[j] = p[(size_t)j * 16384];

    for (int g = 0; g < 5; ++g) {             // 5 groups x 8 = 40 iters
#pragma unroll
      for (int k = 0; k < 8; ++k) {
        const int chl = g * 8 + k;
        float4 cur = buf[k];
        int nxt = chl + 8; if (nxt > 39) nxt = 39;     // scalar min, no branch
        buf[k] = p[(size_t)nxt * 16384];               // unconditional prefetch
        const float4* cf = (const float4*)(scoef + chl * 16);
        float4 c0 = cf[0], c1 = cf[1], c2 = cf[2], c3 = cf[3];
        float cw[16] = {c0.x, c0.y, c0.z, c0.w, c1.x, c1.y, c1.z, c1.w,
                        c2.x, c2.y, c2.z, c2.w, c3.x, c3.y, c3.z, c3.w};
#pragma unroll
        for (int r = 0; r < 16; ++r) {
          float tt = cur.x * rv[r].x + cur.y * rv[r].y + cur.z * rv[r].z + cur.w * rv[r].w;
          acc[r] = fmaf(cw[r], tt, acc[r]);
        }
      }
    }

#pragma unroll
    for (int m = 1; m <= 16; m <<= 1) {
#pragma unroll
      for (int r = 0; r < 16; ++r) acc[r] += __shfl_xor(acc[r], m, 64);
    }
    if (l32 == 0) {
      const int f = fp * 2 + (lane >> 5);
#pragma unroll
      for (int r = 0; r < 16; ++r) atomicAdd(&ws[WS_WEFF + r * 512 + f], acc[r]);
    }
  } else if (blk < 2064) {
    // ---- Role B1: Weff += coef * fc1_b. fc1_b flat index = ch*512 + f.
    const int bb = blk - 2048;                // 0..15
    const int f = (bb & 1) * 256 + t;
    const int ch0 = (bb >> 1) * 160;
    for (int i = t; i < 2560; i += 256) {
      int chl = i >> 4, r = i & 15;
      int ch = ch0 + chl, c = ch >> 7, h = ch & 127;
      scoef[i] = ws[WS_WT + c * 16 + r] * ws[WS_W2T + h * 16 + r];
    }
    __syncthreads();
    float acc[16];
#pragma unroll
    for (int r = 0; r < 16; ++r) acc[r] = 0.f;
    const float* q = fc1_b + (size_t)ch0 * 512 + f;
    // depth-4 unconditional pipeline (160 iters, tail clamped)
    float b4[4];
#pragma unroll
    for (int j = 0; j < 4; ++j) b4[j] = q[(size_t)j * 512];
    for (int g = 0; g < 40; ++g) {
#pragma unroll
      for (int k = 0; k < 4; ++k) {
        const int it = g * 4 + k;
        float xv = b4[k];
        int nxt = it + 4; if (nxt > 159) nxt = 159;
        b4[k] = q[(size_t)nxt * 512];
        const float4* cf = (const float4*)(scoef + it * 16);
        float4 c0 = cf[0], c1 = cf[1], c2 = cf[2], c3 = cf[3];
        float cw[16] = {c0.x, c0.y, c0.z, c0.w, c1.x, c1.y, c1.z, c1.w,
                        c2.x, c2.y, c2.z, c2.w, c3.x, c3.y, c3.z, c3.w};
#pragma unroll
        for (int r = 0; r < 16; ++r) acc[r] = fmaf(cw[r], xv, acc[r]);
      }
    }
#pragma unroll
    for (int r = 0; r < 16; ++r) atomicAdd(&ws[WS_WEFF + r * 512 + f], acc[r]);
  } else if (blk < 2072) {
    // ---- Role H: bfin += coef * (b1_w[ch,:]·rv). b1_w flat = ch*128 + d.
    const int hb = blk - 2064;                // 0..7
    const int wid = t >> 6, lane = t & 63;
    const int ch0b = hb * 160;
    for (int i = t; i < 2560; i += 256) {
      int chl = i >> 4, r = i & 15;
      int ch = ch0b + chl, c = ch >> 7, h = ch & 127;
      scoef[i] = ws[WS_WT + c * 16 + r] * ws[WS_W2T + h * 16 + r];
    }
    __syncthreads();
    float2 rv2[16];
#pragma unroll
    for (int r = 0; r < 16; ++r) rv2[r] = *(const float2*)&ws[WS_RV + r * 128 + lane * 2];
    float acc[16];
#pragma unroll
    for (int r = 0; r < 16; ++r) acc[r] = 0.f;
    const int chl0 = wid * 40;
    const float2* q = (const float2*)b1_w + (size_t)(ch0b + chl0) * 64 + lane;
    float2 b2buf[4];
#pragma unroll
    for (int j = 0; j < 4; ++j) b2buf[j] = q[(size_t)j * 64];
    for (int g = 0; g < 10; ++g) {
#pragma unroll
      for (int k = 0; k < 4; ++k) {
        const int it = g * 4 + k;
        float2 cur = b2buf[k];
        int nxt = it + 4; if (nxt > 39) nxt = 39;
        b2buf[k] = q[(size_t)nxt * 64];
        const float4* cf = (const float4*)(scoef + (chl0 + it) * 16);
        float4 c0 = cf[0], c1 = cf[1], c2 = cf[2], c3 = cf[3];
        float cw[16] = {c0.x, c0.y, c0.z, c0.w, c1.x, c1.y, c1.z, c1.w,
                        c2.x, c2.y, c2.z, c2.w, c3.x, c3.y, c3.z, c3.w};
#pragma unroll
        for (int r = 0; r < 16; ++r)
          acc[r] = fmaf(cw[r], cur.x * rv2[r].x + cur.y * rv2[r].y, acc[r]);
      }
    }
#pragma unroll
    for (int m = 1; m <= 32; m <<= 1) {
#pragma unroll
      for (int r = 0; r < 16; ++r) acc[r] += __shfl_xor(acc[r], m, 64);
    }
    if (lane == 0) {
#pragma unroll
      for (int r = 0; r < 16; ++r) bfred[wid][r] = acc[r];
    }
    __syncthreads();
    if (t < 16)
      atomicAdd(&ws[WS_BFIN + t], bfred[0][t] + bfred[1][t] + bfred[2][t] + bfred[3][t]);
  } else {
    // ---- small terms: coef·b1_b + (w·rv)·b2_w + w·b2_b
    const int wid = t >> 6, lane = t & 63;
    float acc[16];
#pragma unroll
    for (int r = 0; r < 16; ++r) acc[r] = 0.f;
    for (int i = t; i < 1280; i += 256) {
      int c = i >> 7, h = i & 127;
      float v = b1_b[c * 128 + h];
#pragma unroll
      for (int r = 0; r < 16; ++r)
        acc[r] = fmaf(ws[WS_WT + c * 16 + r] * ws[WS_W2T + h * 16 + r], v, acc[r]);
    }
    for (int i = t; i < 1280; i += 256) {
      int c = i >> 7, d = i & 127;
      float v = b2_w[c * 128 + d];
#pragma unroll
      for (int r = 0; r < 16; ++r)
        acc[r] = fmaf(ws[WS_WT + c * 16 + r] * ws[WS_RV + r * 128 + d], v, acc[r]);
    }
    if (t < 10) {
      float v = b2_b[t];
#pragma unroll
      for (int r = 0; r < 16; ++r) acc[r] = fmaf(ws[WS_WT + t * 16 + r], v, acc[r]);
    }
#pragma unroll
    for (int m = 1; m <= 32; m <<= 1) {
#pragma unroll
      for (int r = 0; r < 16; ++r) acc[r] += __shfl_xor(acc[r], m, 64);
    }
    if (lane == 0) {
#pragma unroll
      for (int r = 0; r < 16; ++r) bfred[wid][r] = acc[r];
    }
    __syncthreads();
    if (t < 16)
      atomicAdd(&ws[WS_BFIN + t], bfred[0][t] + bfred[1][t] + bfred[2][t] + bfred[3][t]);
  }
}

// ---------------- K5: Wfin = Weff @ base_w ; bfin += Weff·base_b ----------------
__global__ __launch_bounds__(256) void k_wfin(const float* __restrict__ base_w,
                                              const float* __restrict__ base_b,
                                              float* __restrict__ ws) {
  const int t = threadIdx.x;
  const int blk = blockIdx.x;             // 128 = 4 i-tiles x 32 f-chunks
  const int i = (blk & 3) * 256 + t;
  const int f0 = (blk >> 2) * 16;
  const float* WEFF = ws + WS_WEFF;
  float acc[16];
#pragma unroll
  for (int r = 0; r < 16; ++r) acc[r] = 0.f;
#pragma unroll 4
  for (int f = f0; f < f0 + 16; ++f) {
    float bw = base_w[(size_t)f * 1024 + i];
#pragma unroll
    for (int r = 0; r < 16; ++r) acc[r] = fmaf(WEFF[r * 512 + f], bw, acc[r]);
  }
#pragma unroll
  for (int r = 0; r < 16; ++r) atomicAdd(&ws[WS_WFIN + r * 1024 + i], acc[r]);

  if (blk == 0 && t < 64) {
    float a2[16];
#pragma unroll
    for (int r = 0; r < 16; ++r) a2[r] = 0.f;
    for (int f = t; f < 512; f += 64) {
      float v = base_b[f];
#pragma unroll
      for (int r = 0; r < 16; ++r) a2[r] = fmaf(WEFF[r * 512 + f], v, a2[r]);
    }
#pragma unroll
    for (int m = 1; m <= 32; m <<= 1) {
#pragma unroll
      for (int r = 0; r < 16; ++r) a2[r] += __shfl_xor(a2[r], m, 64);
    }
    if (t == 0) {
#pragma unroll
      for (int r = 0; r < 16; ++r) atomicAdd(&ws[WS_BFIN + r], a2[r]);
    }
  }
}

// ---------------- K6: out[r,b] = x[b,:]·Wfin[r,:] + bfin[r]; sigmoid + raw ----------------
__global__ __launch_bounds__(256) void k_out(const float* __restrict__ x,
                                             const float* __restrict__ ws,
                                             float* __restrict__ out) {
  __shared__ float4 wfs[4096];            // 64 KB: Wfin as [r*256 + i4]
  const int t = threadIdx.x;
  const float4* wf4 = (const float4*)(ws + WS_WFIN);
#pragma unroll
  for (int k = 0; k < 16; ++k) wfs[t + 256 * k] = wf4[t + 256 * k];
  __syncthreads();

  const int b0 = blockIdx.x * 16;
  const int bp = t >> 5;                  // 0..7 (b-pair)
  const int isub = t & 31;
  const int bA = b0 + bp * 2;
  const float* xa = x + (size_t)bA * 1024;
  const float* xb = xa + 1024;
  float acc0[16], acc1[16];
#pragma unroll
  for (int r = 0; r < 16; ++r) { acc0[r] = 0.f; acc1[r] = 0.f; }

  for (int chunk = 0; chunk < 4; ++chunk) {
#pragma unroll
    for (int j = 0; j < 2; ++j) {
      const int off = chunk * 256 + j * 128 + isub * 4;
      float4 xv0 = *(const float4*)&xa[off];
      float4 xv1 = *(const float4*)&xb[off];
      const float4* wrow = wfs + chunk * 64 + j * 32 + isub;
#pragma unroll
      for (int r = 0; r < 16; ++r) {
        float4 w = wrow[r * 256];
        acc0[r] += xv0.x * w.x + xv0.y * w.y + xv0.z * w.z + xv0.w * w.w;
        acc1[r] += xv1.x * w.x + xv1.y * w.y + xv1.z * w.z + xv1.w * w.w;
      }
    }
  }
#pragma unroll
  for (int m = 1; m <= 16; m <<= 1) {
#pragma unroll
    for (int r = 0; r < 16; ++r) {
      acc0[r] += __shfl_xor(acc0[r], m, 64);
      acc1[r] += __shfl_xor(acc1[r], m, 64);
    }
  }
  if (isub == 0) {
#pragma unroll
    for (int r = 0; r < 16; ++r) {
      float bf = ws[WS_BFIN + r];
      float v0 = acc0[r] + bf;
      float v1 = acc1[r] + bf;
      out[r * 4096 + bA] = 1.f / (1.f + expf(-v0));
      out[r * 4096 + bA + 1] = 1.f / (1.f + expf(-v1));
      out[65536 + r * 4096 + bA] = v0;
      out[65536 + r * 4096 + bA + 1] = v1;
    }
  }
}

extern "C" void kernel_launch(void* const* d_in, const int* in_sizes, int n_in,
                              void* d_out, int out_size, void* d_ws, size_t ws_size,
                              hipStream_t stream) {
  (void)in_sizes; (void)n_in; (void)out_size; (void)ws_size;
  const float* x      = (const float*)d_in[0];
  const float* pref   = (const float*)d_in[1];
  const float* base_w = (const float*)d_in[2];
  const float* base_b = (const float*)d_in[3];
  const float* wm1_w  = (const float*)d_in[4];
  const float* wm1_b  = (const float*)d_in[5];
  const float* wm2_w  = (const float*)d_in[6];
  const float* wm2_b  = (const float*)d_in[7];
  const float* ray0_w = (const float*)d_in[8];
  const float* ray0_b = (const float*)d_in[9];
  const float* ray2_w = (const float*)d_in[10];
  const float* ray2_b = (const float*)d_in[11];
  const float* fc1_w  = (const float*)d_in[12];
  const float* fc1_b  = (const float*)d_in[13];
  const float* b1_w   = (const float*)d_in[14];
  const float* b1_b   = (const float*)d_in[15];
  const float* fc2_w  = (const float*)d_in[16];
  const float* fc2_b  = (const float*)d_in[17];
  const float* b2_w   = (const float*)d_in[18];
  const float* b2_b   = (const float*)d_in[19];
  float* ws  = (float*)d_ws;
  float* out = (float*)d_out;

  hipMemsetAsync(ws + WS_ZERO_BEG, 0, (size_t)WS_ZERO_CNT * sizeof(float), stream);
  k_stage1<<<80, 256, 0, stream>>>(pref, wm1_w, wm1_b, wm2_w, wm2_b,
                                   ray0_w, ray0_b, ray2_w, ray2_b, fc2_b, ws);
  k_stage2<<<80, 256, 0, stream>>>(fc2_w, ws);
  k_main<<<2073, 256, 0, stream>>>(fc1_w, fc1_b, b1_w, b1_b, b2_w, b2_b, ws);
  k_wfin<<<128, 256, 0, stream>>>(base_w, base_b, ws);
  k_out<<<256, 256, 0, stream>>>(x, ws, out);
}